// Round 1
// baseline (555.436 us; speedup 1.0000x reference)
//
#include <hip/hip_runtime.h>
#include <stdint.h>
#include <string.h>

// B=4,H=16,L=1024,D=64. q,k: fp32 [B,H,L,D]; mask: byte or int32 bool
// (per-block runtime detection); out: fp32 [B,H,L,L].
// out[bh,i,j] = mask ? 0 : sum_d exp(-(qs-ks)^2)/64, rank-paired via stable
// per-(bh,d) argsort of q and k columns.
//
// phase1 (REWRITTEN this round): one WAVE per (bh,d) column-pair, 16 elems
//         per thread (e = 16*lane + s). Full bitonic argsort on u64 keys
//         {f2ord(fp32)<<32 | idx}: j=1..8 in-register (compile-time dirs for
//         k2<=8), j=16..512 via __shfl_xor (m=j/16<=32). ZERO barriers, zero
//         LDS sort stages (old E=4 version had 3 LDS CE stages + 2 reg<->LDS
//         roundtrips + 6 syncthreads). LDS only as 4KiB wave-private scatter
//         buffer for the packed {val,k-index} epilogue.
//         Block = 4 waves = 4 consecutive d of one bh (shared cache lines).
// phase2: UNCHANGED from 551-us baseline (near its ~56us traffic floor).

#define LL 1024
#define DD 64
#define NBH 64
#define PAIRS_BYTES ((size_t)NBH * DD * LL * 4)   // 16 MiB

typedef float    vf4   __attribute__((ext_vector_type(4)));
typedef uint32_t vu4   __attribute__((ext_vector_type(4)));
typedef int32_t  vi4   __attribute__((ext_vector_type(4)));

__device__ __forceinline__ uint32_t f2ord(float x) {
    uint32_t u = __float_as_uint(x);
    return (u & 0x80000000u) ? ~u : (u | 0x80000000u);
}
__device__ __forceinline__ float ord2f(uint32_t o) {
    uint32_t u = (o & 0x80000000u) ? (o & 0x7fffffffu) : ~o;
    return __uint_as_float(u);
}

// ---------- phase 1: 16-elem/thread wave-autonomous bitonic argsort --------
__global__ __launch_bounds__(256, 3) void swd3_phase1(
    const float* __restrict__ q, const float* __restrict__ k,
    uint32_t* __restrict__ pairs)
{
    __shared__ alignas(16) uint32_t pr[4][LL];      // 4 KiB per wave, private

    const int raw  = blockIdx.x;                    // 0..1023
    const int slot = raw >> 3;                      // 0..127
    const int bh   = (raw & 7) * 8 + (slot >> 4);   // XCD swizzle: same bh
    const int dg   = slot & 15;                     //   -> same XCD
    const int t    = threadIdx.x;
    const int w    = t >> 6;                        // wave 0..3
    const int lane = t & 63;
    const int d    = dg * 4 + w;                    // 4 adjacent d per block

    const size_t colbase = (size_t)bh * (LL * DD) + d;

    // thread owns elements e = 16*lane + s, s = 0..15
    uint64_t xq[16], xk[16];
    #pragma unroll
    for (int s = 0; s < 16; ++s) {
        const uint32_t e = 16u * (uint32_t)lane + (uint32_t)s;
        xq[s] = ((uint64_t)f2ord(q[colbase + (size_t)e * DD]) << 32) | e;
        xk[s] = ((uint64_t)f2ord(k[colbase + (size_t)e * DD]) << 32) | e;
    }

    auto cex = [](uint64_t& a, uint64_t& b, bool up) {
        const uint64_t lo = a < b ? a : b;
        const uint64_t hi = a < b ? b : a;
        a = up ? lo : hi; b = up ? hi : lo;
    };
    auto shfl64 = [](uint64_t v, int m) -> uint64_t {
        const uint32_t lo = __shfl_xor((uint32_t)v, m);
        const uint32_t hi = __shfl_xor((uint32_t)(v >> 32), m);
        return ((uint64_t)hi << 32) | lo;
    };
    auto shfl_step = [&](int m, bool up) {          // j = 16*m, m = 1..32
        const bool keepmin = (((lane & m) == 0) == up);
        #pragma unroll
        for (int s = 0; s < 16; ++s) {
            uint64_t y = shfl64(xq[s], m);
            xq[s] = keepmin ? (xq[s] < y ? xq[s] : y) : (xq[s] > y ? xq[s] : y);
            y = shfl64(xk[s], m);
            xk[s] = keepmin ? (xk[s] < y ? xk[s] : y) : (xk[s] > y ? xk[s] : y);
        }
    };

    // k2 = 2,4,8: fully in-register, directions compile-time per reg index
    #pragma unroll
    for (int lk = 1; lk <= 3; ++lk) {
        const int k2 = 1 << lk;
        #pragma unroll
        for (int j = k2 >> 1; j >= 1; j >>= 1) {
            #pragma unroll
            for (int s = 0; s < 16; ++s) {
                if ((s & j) == 0) {
                    const bool up = ((s & k2) == 0);
                    cex(xq[s], xq[s | j], up);
                    cex(xk[s], xk[s | j], up);
                }
            }
        }
    }
    // k2 = 16: direction uniform per thread (e&16 = 16*(lane&1))
    {
        const bool up = ((lane & 1) == 0);
        #pragma unroll
        for (int j = 8; j >= 1; j >>= 1) {
            #pragma unroll
            for (int s = 0; s < 16; ++s)
                if ((s & j) == 0) { cex(xq[s], xq[s | j], up);
                                    cex(xk[s], xk[s | j], up); }
        }
    }
    // k2 = 32..1024: cross-lane shfl (j=16..512 -> m=1..32), then in-register
    #pragma unroll
    for (int lk = 5; lk <= 10; ++lk) {
        const bool up = ((lane & (1 << (lk - 4))) == 0);  // lk=10 -> always up
        #pragma unroll
        for (int m = 1 << (lk - 5); m >= 1; m >>= 1)
            shfl_step(m, up);
        #pragma unroll
        for (int j = 8; j >= 1; j >>= 1) {
            #pragma unroll
            for (int s = 0; s < 16; ++s)
                if ((s & j) == 0) { cex(xq[s], xq[s | j], up);
                                    cex(xk[s], xk[s | j], up); }
        }
    }

    // epilogue: rank r = 16*lane + s pairs q-rank-r with k-rank-r.
    // Scatter packed {val fp32 (top 22 bits), low10 = k-index} by q-index
    // into the wave-private LDS row, then vectorized coalesced store.
    uint32_t* prw = pr[w];
    #pragma unroll
    for (int s = 0; s < 16; ++s) {
        const uint32_t iq = (uint32_t)xq[s] & 1023u;
        const uint32_t ik = (uint32_t)xk[s] & 1023u;
        const float df = ord2f((uint32_t)(xq[s] >> 32))
                       - ord2f((uint32_t)(xk[s] >> 32));
        const float val = __expf(-df * df) * (1.0f / 64.0f);
        prw[iq] = (__float_as_uint(val) & 0xFFFFFC00u) | ik;   // rel err<2^-12
    }
    __asm__ volatile("s_waitcnt lgkmcnt(0)" ::: "memory");  // wave-local drain
    vu4* pp4 = (vu4*)(pairs + ((size_t)bh * DD + d) * LL);
    const vu4* src = (const vu4*)prw;
    #pragma unroll
    for (int r = 0; r < 4; ++r)
        pp4[r * 64 + lane] = src[r * 64 + lane];
}

// ---------- phase 2: inline detect + prefetch + assembly + NT write --------
// UNCHANGED from baseline.
__global__ __launch_bounds__(256) void swd3_phase2(
    const uint32_t* __restrict__ pairs, const void* __restrict__ maskp,
    float* __restrict__ out)
{
    __shared__ alignas(16) float acc[8 * LL];       // 32 KiB
    __shared__ uint32_t sdet[4];

    const int bh = blockIdx.x >> 7;
    const int s  = blockIdx.x & 127;
    const int i0 = s * 8;
    const int t  = threadIdx.x;

    // inline mask-width detect on the globally-shared first 1 KiB of mask
    {
        const uint32_t w = ((const uint32_t*)maskp)[t];
        const uint64_t bal = __ballot(w > 1u);
        if ((t & 63) == 0) sdet[t >> 6] = (bal != 0ull) ? 1u : 0u;
    }

    vf4* acc4 = (vf4*)acc;
    #pragma unroll
    for (int v = 0; v < 8; ++v) {
        vf4 z; z.x = 0.f; z.y = 0.f; z.z = 0.f; z.w = 0.f;
        acc4[v * 256 + t] = z;
    }
    __syncthreads();

    const bool mask_byte =
        ((sdet[0] | sdet[1] | sdet[2] | sdet[3]) != 0u);
    const size_t cellbase = ((size_t)bh << 20) + ((size_t)i0 << 10);

    // prefetch mask into registers (NT); loads fly during the LDS scatter
    uint32_t mb[8];
    vi4      mi[8];
    if (mask_byte) {
        const uint32_t* mp = (const uint32_t*)maskp + (cellbase >> 2);
        #pragma unroll
        for (int v = 0; v < 8; ++v)
            mb[v] = __builtin_nontemporal_load(mp + v * 256 + t);
    } else {
        const vi4* mp = (const vi4*)((const int32_t*)maskp + cellbase);
        #pragma unroll
        for (int v = 0; v < 8; ++v)
            mi[v] = __builtin_nontemporal_load(mp + v * 256 + t);
    }

    // 512 records as 256 uint2: thread t -> dd=t>>2, rows 2*(t&3), 2*(t&3)+1
    {
        const uint32_t* pb = pairs + (size_t)bh * (DD * LL);
        const int dd = t >> 2;
        const uint2 pv = ((const uint2*)(pb + dd * LL + i0))[t & 3];
        const int ii0 = 2 * (t & 3), ii1 = ii0 + 1;
        atomicAdd(&acc[ii0 * LL + (int)(pv.x & 1023u)],
                  __uint_as_float(pv.x & 0xFFFFFC00u));
        atomicAdd(&acc[ii1 * LL + (int)(pv.y & 1023u)],
                  __uint_as_float(pv.y & 0xFFFFFC00u));
    }
    __syncthreads();

    vf4* ob = (vf4*)(out + cellbase);
    #pragma unroll
    for (int v = 0; v < 8; ++v) {
        const int p = v * 256 + t;                  // vf4 group in [0,2048)
        const vf4 a = acc4[p];
        int mx, my, mz, mw2;
        if (mask_byte) {
            const uint32_t m = mb[v];
            mx = (int)(m & 0xFFu); my = (int)((m >> 8) & 0xFFu);
            mz = (int)((m >> 16) & 0xFFu); mw2 = (int)(m >> 24);
        } else {
            mx = mi[v].x; my = mi[v].y; mz = mi[v].z; mw2 = mi[v].w;
        }
        vf4 r;
        r.x = mx  ? 0.f : a.x;
        r.y = my  ? 0.f : a.y;
        r.z = mz  ? 0.f : a.z;
        r.w = mw2 ? 0.f : a.w;
        __builtin_nontemporal_store(r, ob + p);
    }
}

extern "C" void kernel_launch(void* const* d_in, const int* in_sizes, int n_in,
                              void* d_out, int out_size, void* d_ws, size_t ws_size,
                              hipStream_t stream) {
    const float* q = (const float*)d_in[0];
    const float* k = (const float*)d_in[1];
    const void* mask = d_in[2];
    uint32_t* pairs = (uint32_t*)d_ws;

    const bool ws_ok = (ws_size >= PAIRS_BYTES);
    hipError_t e1 = hipSuccess, e2 = hipSuccess;
    (void)hipGetLastError();

    if (ws_ok) {
        swd3_phase1<<<NBH * DD / 4, 256, 0, stream>>>(q, k, pairs);
        e1 = hipGetLastError();
        swd3_phase2<<<NBH * 128, 256, 0, stream>>>(pairs, mask, (float*)d_out);
        e2 = hipGetLastError();
    }

    if (!ws_ok || e1 != hipSuccess || e2 != hipSuccess) {
        // Diagnostic stamp (fp32 codes): absmax reveals which enqueue failed.
        static float h_stamp[8];
        h_stamp[0] = !ws_ok ? (9000.0f + (float)(ws_size >> 20))
                            : (1000.0f + (float)(int)e1);
        h_stamp[1] = 2000.0f + (float)(int)e2;
        h_stamp[2] = h_stamp[0];
        h_stamp[3] = h_stamp[1];
        hipMemcpyAsync(d_out, h_stamp, sizeof(h_stamp),
                       hipMemcpyHostToDevice, stream);
    }
}